// Round 8
// baseline (347.519 us; speedup 1.0000x reference)
//
#include <hip/hip_runtime.h>
#include <math.h>

#define NN 100000
#define EE 1600000
#define HID 64
#define BKT 391                 // ceil(NN/256) buckets of 256 nodes
#define SLAB 5504               // slab capacity per bucket (mean true ~4092, padded ~4476)
#define SLAB_IT ((SLAB + 255) / 256)     // 22 per-thread iterations in build
#define CHUNK 4096              // edges per workgroup in placement pass
#define NWG ((EE + CHUNK - 1) / CHUNK)   // 391
#define TB (NN / 16)            // 6250 gather/transform blocks (4 waves x 4 nodes)

typedef _Float16 f16;
typedef _Float16 f16x2 __attribute__((ext_vector_type(2)));
typedef int i32x4 __attribute__((ext_vector_type(4)));
typedef unsigned u32x4 __attribute__((ext_vector_type(4)));

__device__ __forceinline__ f16x2 u2h(unsigned u) { return __builtin_bit_cast(f16x2, u); }
__device__ __forceinline__ unsigned h2u(f16x2 h) { return __builtin_bit_cast(unsigned, h); }

#if defined(__has_builtin) && __has_builtin(__builtin_amdgcn_fdot2)
__device__ __forceinline__ float dot2(f16x2 a, f16x2 b, float c) {
    return __builtin_amdgcn_fdot2(a, b, c, false);
}
#else
__device__ __forceinline__ float dot2(f16x2 a, f16x2 b, float c) {
    c = fmaf((float)a.x, (float)b.x, c);
    return fmaf((float)a.y, (float)b.y, c);
}
#endif

// ===================== fp8 (OCP e4m3) helpers (r18, kept) =====================
// Ladder: r18 fp8 -3%; r19 VMEM 16->10 -11%; r20 paired rows NULL (in-flight
// LINES unchanged at 8/quarter -> concurrency is the resource, per r20 null).
// r21: nt-stream everything except A row loads -> protect A's L2 residency
// (measured: FETCH 61MB vs 6.4MB array = ~50% L2 miss on rows).

#if defined(__has_builtin)
#if __has_builtin(__builtin_amdgcn_cvt_pk_f32_fp8) && __has_builtin(__builtin_amdgcn_cvt_pk_fp8_f32)
#define HW_FP8 1
#endif
#endif

#ifndef HW_FP8
__device__ __forceinline__ float dec_e4m3(unsigned b) {
    unsigned s = b >> 7, e = (b >> 3) & 0xF, m = b & 7;
    float v;
    if (e == 0) v = (float)m * 0.001953125f;                 // m * 2^-9
    else v = (1.f + (float)m * 0.125f) * exp2f((float)((int)e - 7));
    return s ? -v : v;
}
__device__ __forceinline__ unsigned char enc_e4m3(float x) {
    unsigned s = (__builtin_bit_cast(unsigned, x) >> 31) << 7;
    float a = fabsf(x);
    if (!(a < 464.f)) return (unsigned char)(s | 0x7E);      // clamp / NaN->max
    int e; float m = frexpf(a, &e);                          // a = m*2^e, m in [0.5,1)
    int E = e - 1;
    unsigned bits;
    if (E < -6) {
        int n = (int)rintf(a * 512.f);
        bits = (n > 7) ? 0x08u : (unsigned)n;
    } else {
        int n = (int)rintf((2.f * m - 1.f) * 8.f);
        if (n == 8) { n = 0; E += 1; }
        if (E > 8) return (unsigned char)(s | 0x7E);
        bits = ((unsigned)(E + 7) << 3) | (unsigned)n;
    }
    return (unsigned char)(s | bits);
}
#endif

__device__ __forceinline__ void acc_fp8(unsigned v, float& a0, float& a1,
                                        float& a2, float& a3) {
#ifdef HW_FP8
    auto lo = __builtin_amdgcn_cvt_pk_f32_fp8((int)v, false);
    auto hi = __builtin_amdgcn_cvt_pk_f32_fp8((int)v, true);
    a0 += lo[0]; a1 += lo[1]; a2 += hi[0]; a3 += hi[1];
#else
    a0 += dec_e4m3(v & 0xFFu);         a1 += dec_e4m3((v >> 8) & 0xFFu);
    a2 += dec_e4m3((v >> 16) & 0xFFu); a3 += dec_e4m3(v >> 24);
#endif
}

__device__ __forceinline__ unsigned char enc_fp8(float x) {
#ifdef HW_FP8
    return (unsigned char)(__builtin_amdgcn_cvt_pk_fp8_f32(x, x, 0, false) & 0xFF);
#else
    return enc_e4m3(x);
#endif
}

// ================= merged: CSR placement (blocks 0..NWG-1) ====================
// ================= || layer-0 transform + weight pack (blocks NWG..) ==========
// r21: transform back to 4 nodes/wave (r20's 8n regressed 49.8->53, occupancy
// 55->41%). Streams (dst/src/pairs/hn8/hrb) are nt. Sentinel zero-rows folded
// in (block bb==40) -> two memset dispatches removed.

__global__ void mt_kernel(const int* __restrict__ src, const int* __restrict__ dst,
                          int* __restrict__ bfill, unsigned* __restrict__ pairs,
                          const float* __restrict__ h,
                          const float* __restrict__ Wn, const float* __restrict__ bn,
                          const float* __restrict__ Wr,
                          unsigned char* __restrict__ hn8, f16* __restrict__ hrb,
                          unsigned char* __restrict__ hn8b,
                          const float* __restrict__ Wn1, const float* __restrict__ Wr1,
                          const float* __restrict__ Wn2, const float* __restrict__ Wr2,
                          const float* __restrict__ Wp1, unsigned* __restrict__ w16) {
    __shared__ int lc[BKT];
    __shared__ int lbase[BKT];
    int t = threadIdx.x;

    if (blockIdx.x < NWG) {
        // ---- CSR placement (bucketized; r16 proved random scatter >100us) ----
        for (int b = t; b < BKT; b += 256) lc[b] = 0;
        __syncthreads();
        int base = blockIdx.x * CHUNK;
        int myd[CHUNK / 256];
        int myr[CHUNK / 256];
#pragma unroll
        for (int j = 0; j < CHUNK / 256; ++j) {
            int i = base + j * 256 + t;
            myd[j] = (i < EE) ? __builtin_nontemporal_load(dst + i) : -1;
            myr[j] = (myd[j] >= 0) ? atomicAdd(&lc[myd[j] >> 8], 1) : 0;
        }
        __syncthreads();
        for (int b = t; b < BKT; b += 256) {
            int c = lc[b];
            if (c) {
                int ofs = atomicAdd(&bfill[b], c);
                if (ofs + c > SLAB) ofs = SLAB - c;   // statistically unreachable
                lbase[b] = b * SLAB + ofs;
            }
        }
        __syncthreads();
#pragma unroll
        for (int j = 0; j < CHUNK / 256; ++j) {
            int i = base + j * 256 + t;
            if (myd[j] >= 0) {
                int b = myd[j] >> 8;
                unsigned pk = (unsigned)__builtin_nontemporal_load(src + i)
                              | ((unsigned)(myd[j] & 255) << 24);
                __builtin_nontemporal_store(pk, &pairs[lbase[b] + myr[j]]);
            }
        }
        return;
    }

    int bb = blockIdx.x - NWG;

    // ---- f16 weight pack (first 40 transform blocks) ----
    if (bb < 40) {
        int id = bb * 256 + t;
        int mat = id >> 11;            // 0..4
        int p = (id >> 6) & 31;        // pair index
        int j = id & 63;               // output column
        const float* W = (mat == 0) ? Wn1 : (mat == 1) ? Wr1 :
                         (mat == 2) ? Wn2 : (mat == 3) ? Wr2 : Wp1;
        f16x2 v;
        v.x = (f16)W[(2 * p) * HID + j];
        v.y = (f16)W[(2 * p + 1) * HID + j];
        w16[id] = h2u(v);
    }
    // ---- sentinel zero rows (x4-padding target, node NN) ----
    if (bb == 40 && t < 32) {
        if (t < 16) ((unsigned*)(hn8  + (size_t)NN * HID))[t] = 0;
        else        ((unsigned*)(hn8b + (size_t)NN * HID))[t - 16] = 0;
    }

    // ---- layer-0 transform: 4 nodes/wave, lane = output column ----
    int lane = t & 63;
    int wid = (bb * 256 + t) >> 6;
    int m0 = __builtin_amdgcn_readfirstlane(wid << 2);
    const float* h0 = h + (size_t)m0 * 32;

    float an0 = 0.f, an1 = 0.f, an2 = 0.f, an3 = 0.f;
    float ar0 = 0.f, ar1 = 0.f, ar2 = 0.f, ar3 = 0.f;
#pragma unroll
    for (int k = 0; k < 32; ++k) {
        float wn = Wn[k * HID + lane];
        float wr = Wr[k * HID + lane];
        float hk0 = h0[k], hk1 = h0[32 + k], hk2 = h0[64 + k], hk3 = h0[96 + k];
        an0 = fmaf(hk0, wn, an0); ar0 = fmaf(hk0, wr, ar0);
        an1 = fmaf(hk1, wn, an1); ar1 = fmaf(hk1, wr, ar1);
        an2 = fmaf(hk2, wn, an2); ar2 = fmaf(hk2, wr, ar2);
        an3 = fmaf(hk3, wn, an3); ar3 = fmaf(hk3, wr, ar3);
    }
    float b = bn[lane];
    size_t o8 = (size_t)m0 * HID + lane;        // fp8: 1 byte per feature
    size_t o = (size_t)m0 * HID + lane;
    __builtin_nontemporal_store(enc_fp8(an0), hn8 + o8);
    __builtin_nontemporal_store(enc_fp8(an1), hn8 + o8 + HID);
    __builtin_nontemporal_store(enc_fp8(an2), hn8 + o8 + 2 * HID);
    __builtin_nontemporal_store(enc_fp8(an3), hn8 + o8 + 3 * HID);
    __builtin_nontemporal_store((f16)(ar0 + b), hrb + o);
    __builtin_nontemporal_store((f16)(ar1 + b), hrb + o + HID);
    __builtin_nontemporal_store((f16)(ar2 + b), hrb + o + 2 * HID);
    __builtin_nontemporal_store((f16)(ar3 + b), hrb + o + 3 * HID);
}

// ================= per-bucket counting sort (r17 register form) ===============
// r19: per-node segments padded to x4 with sentinel node NN (zero row). rs/re
// keep the TRUE range; slots [re, rs+pad4) hold NN. inv uses true count.
// r21: pairs reads / col writes nt.

__global__ void build_kernel(const unsigned* __restrict__ pairs,
                             const int* __restrict__ bfill,
                             int* __restrict__ rs, int* __restrict__ re,
                             float* __restrict__ inv, int* __restrict__ col) {
    __shared__ int ncnt[256];
    __shared__ int nexcl[256];
    int b = blockIdx.x;
    int t = threadIdx.x;
    int s0 = b * SLAB;
    int ce = bfill[b]; if (ce > SLAB) ce = SLAB;
    ncnt[t] = 0;
    __syncthreads();
    unsigned mypk[SLAB_IT];
    int myr[SLAB_IT];
#pragma unroll
    for (int j = 0; j < SLAB_IT; ++j) {
        int e = j * 256 + t;
        if (e < ce) {
            unsigned pk = __builtin_nontemporal_load(pairs + s0 + e);
            mypk[j] = pk;
            myr[j] = atomicAdd(&ncnt[pk >> 24], 1);
        }
    }
    __syncthreads();
    int c = ncnt[t];                  // true count
    int c4 = (c + 3) & ~3;            // padded count
    nexcl[t] = c4;
    __syncthreads();
    for (int off = 1; off < 256; off <<= 1) {
        int u = (t >= off) ? nexcl[t - off] : 0;
        __syncthreads();
        nexcl[t] += u;
        __syncthreads();
    }
    int excl = nexcl[t] - c4;         // padded exclusive base
    int node = (b << 8) + t;
    if (node < NN) {
        int start = s0 + excl; if (start > s0 + SLAB) start = s0 + SLAB;
        int end = start + c;   if (end > s0 + SLAB) end = s0 + SLAB;
        rs[node] = start;
        re[node] = end;
        inv[node] = (c > 0) ? (1.0f / (float)c) : 0.0f;
    }
    __syncthreads();
    ncnt[t] = excl;          // repurpose: per-key padded exclusive base
    __syncthreads();
#pragma unroll
    for (int j = 0; j < SLAB_IT; ++j) {
        int e = j * 256 + t;
        if (e < ce) {
            unsigned pk = mypk[j];
            int idx = s0 + ncnt[pk >> 24] + myr[j];
            if (idx < s0 + SLAB)
                __builtin_nontemporal_store((int)(pk & 0xFFFFFFu), col + idx);
        }
    }
    // sentinel pads (zero row NN): slots [excl+c, excl+c4)
    for (int k = c; k < c4; ++k) {
        int idx = s0 + excl + k;
        if (idx < s0 + SLAB) __builtin_nontemporal_store(NN, col + idx);
    }
}

// ================= paired quarter-wave gather, fp8 rows =======================
// r20 structure kept: quarter = 2 edge-slots x 8 lanes, uint2 row loads
// (2 edges/instr), int4 col loads. r21: col loads nt (streamed 3x, never
// reused within a kernel) so they stop evicting A rows. Row loads stay cached.

__device__ __forceinline__ void acc8(uint2 v, float& a0, float& a1, float& a2,
                                     float& a3, float& a4, float& a5, float& a6,
                                     float& a7) {
    acc_fp8(v.x, a0, a1, a2, a3);
    acc_fp8(v.y, a4, a5, a6, a7);
}

__device__ __forceinline__ void qgp(const uint2* __restrict__ rp2,
                                    const int* __restrict__ col,
                                    int e, int en, int en4, int ff, int el,
                                    float& a0, float& a1, float& a2, float& a3,
                                    float& a4, float& a5, float& a6, float& a7) {
    while (e + 8 <= en4) {
        i32x4 ca = __builtin_nontemporal_load((const i32x4*)(col + e));
        i32x4 cb = __builtin_nontemporal_load((const i32x4*)(col + e + 4));
        int c0 = el ? ca.y : ca.x;
        int c1 = el ? ca.w : ca.z;
        int c2 = el ? cb.y : cb.x;
        int c3 = el ? cb.w : cb.z;
        uint2 v0 = rp2[(size_t)c0 * 8 + ff];
        uint2 v1 = rp2[(size_t)c1 * 8 + ff];
        uint2 v2 = rp2[(size_t)c2 * 8 + ff];
        uint2 v3 = rp2[(size_t)c3 * 8 + ff];
        acc8(v0, a0, a1, a2, a3, a4, a5, a6, a7);
        acc8(v1, a0, a1, a2, a3, a4, a5, a6, a7);
        acc8(v2, a0, a1, a2, a3, a4, a5, a6, a7);
        acc8(v3, a0, a1, a2, a3, a4, a5, a6, a7);
        e += 8;
    }
    if (e + 4 <= en4) {
        i32x4 ca = __builtin_nontemporal_load((const i32x4*)(col + e));
        int c0 = el ? ca.y : ca.x;
        int c1 = el ? ca.w : ca.z;
        uint2 v0 = rp2[(size_t)c0 * 8 + ff];
        uint2 v1 = rp2[(size_t)c1 * 8 + ff];
        acc8(v0, a0, a1, a2, a3, a4, a5, a6, a7);
        acc8(v1, a0, a1, a2, a3, a4, a5, a6, a7);
        e += 4;
    }
    while (e < en) {                  // only reachable if pad clamp fired
        if (!el) {
            uint2 v = rp2[(size_t)col[e] * 8 + ff];
            acc8(v, a0, a1, a2, a3, a4, a5, a6, a7);
        }
        ++e;
    }
}

// ================= fused gather_k + transform_{k+1} ===========================
// hsh byte layout = r19 (node row = 128B linear f16); dot2 epilogue unchanged.
// r21: C reads + all epilogue stores nt.

__global__ void gt_kernel(const unsigned char* __restrict__ An8,
                          const int* __restrict__ rs, const int* __restrict__ re,
                          const int* __restrict__ col, const float* __restrict__ inv,
                          f16* C,
                          const unsigned* __restrict__ Wn16, const float* __restrict__ bn,
                          const unsigned* __restrict__ Wr16,
                          unsigned char* __restrict__ Aout8) {
    __shared__ uint4 hsh[128];        // 4 waves x 4 nodes x 8 uint4 = 2KB
    int t = threadIdx.x;
    int lane = t & 63;
    int wv = t >> 6;
    int wid = (blockIdx.x * blockDim.x + t) >> 6;
    int m0 = wid << 2;
    int m = m0 + (lane >> 4);
    int ff = lane & 7;
    int el = (lane >> 3) & 1;

    int e = rs[m], en = re[m];
    int en4 = e + ((en - e + 3) & ~3);
    int bnd = ((m >> 8) + 1) * SLAB;
    if (en4 > bnd) en4 = bnd;

    float a0 = 0.f, a1 = 0.f, a2 = 0.f, a3 = 0.f;
    float a4 = 0.f, a5 = 0.f, a6 = 0.f, a7 = 0.f;
    qgp((const uint2*)An8, col, e, en, en4, ff, el, a0, a1, a2, a3, a4, a5, a6, a7);

    // combine edge slots (lanes fl and fl^8)
    a0 += __shfl_xor(a0, 8); a1 += __shfl_xor(a1, 8);
    a2 += __shfl_xor(a2, 8); a3 += __shfl_xor(a3, 8);
    a4 += __shfl_xor(a4, 8); a5 += __shfl_xor(a5, 8);
    a6 += __shfl_xor(a6, 8); a7 += __shfl_xor(a7, 8);

    // h_{k+1}[m] = relu(inv*agg + hrb_k[m]); lane (ff) holds feats 8ff..8ff+7
    float iv = inv[m];
    u32x4 cur = __builtin_nontemporal_load((const u32x4*)C + (size_t)m * 8 + ff);
    f16x2 q0 = u2h(cur.x), q1 = u2h(cur.y), q2 = u2h(cur.z), q3 = u2h(cur.w);
    f16x2 p0, p1, p2, p3;
    p0.x = (f16)fmaxf(fmaf(a0, iv, (float)q0.x), 0.f);
    p0.y = (f16)fmaxf(fmaf(a1, iv, (float)q0.y), 0.f);
    p1.x = (f16)fmaxf(fmaf(a2, iv, (float)q1.x), 0.f);
    p1.y = (f16)fmaxf(fmaf(a3, iv, (float)q1.y), 0.f);
    p2.x = (f16)fmaxf(fmaf(a4, iv, (float)q2.x), 0.f);
    p2.y = (f16)fmaxf(fmaf(a5, iv, (float)q2.y), 0.f);
    p3.x = (f16)fmaxf(fmaf(a6, iv, (float)q3.x), 0.f);
    p3.y = (f16)fmaxf(fmaf(a7, iv, (float)q3.y), 0.f);

    uint4 hv4;
    hv4.x = h2u(p0); hv4.y = h2u(p1); hv4.z = h2u(p2); hv4.w = h2u(p3);
    if (!(lane & 8)) hsh[wv * 32 + (lane >> 4) * 8 + ff] = hv4;

    float an[4] = {0.f, 0.f, 0.f, 0.f};
    float ar[4] = {0.f, 0.f, 0.f, 0.f};
#pragma unroll
    for (int j = 0; j < 8; ++j) {     // covers kk = 2j, 2j+1
        f16x2 wn0 = u2h(Wn16[(4 * j) * HID + lane]);
        f16x2 wn1 = u2h(Wn16[(4 * j + 1) * HID + lane]);
        f16x2 wn2 = u2h(Wn16[(4 * j + 2) * HID + lane]);
        f16x2 wn3 = u2h(Wn16[(4 * j + 3) * HID + lane]);
        f16x2 wr0 = u2h(Wr16[(4 * j) * HID + lane]);
        f16x2 wr1 = u2h(Wr16[(4 * j + 1) * HID + lane]);
        f16x2 wr2 = u2h(Wr16[(4 * j + 2) * HID + lane]);
        f16x2 wr3 = u2h(Wr16[(4 * j + 3) * HID + lane]);
#pragma unroll
        for (int n = 0; n < 4; ++n) {
            uint4 d = hsh[wv * 32 + n * 8 + j];   // uniform addr -> broadcast
            an[n] = dot2(u2h(d.x), wn0, an[n]);
            an[n] = dot2(u2h(d.y), wn1, an[n]);
            an[n] = dot2(u2h(d.z), wn2, an[n]);
            an[n] = dot2(u2h(d.w), wn3, an[n]);
            ar[n] = dot2(u2h(d.x), wr0, ar[n]);
            ar[n] = dot2(u2h(d.y), wr1, ar[n]);
            ar[n] = dot2(u2h(d.z), wr2, ar[n]);
            ar[n] = dot2(u2h(d.w), wr3, ar[n]);
        }
    }
    float b = bn[lane];
    size_t o8 = (size_t)m0 * HID + lane;
    size_t o = (size_t)m0 * HID + lane;
#pragma unroll
    for (int n = 0; n < 4; ++n) {
        __builtin_nontemporal_store(enc_fp8(an[n]), Aout8 + o8 + n * HID);
        __builtin_nontemporal_store((f16)(ar[n] + b), C + o + n * HID);
    }
}

// ================= fused gather_2 (no relu) + predictor head ==================

__global__ void gh_kernel(const unsigned char* __restrict__ An8,
                          const int* __restrict__ rs, const int* __restrict__ re,
                          const int* __restrict__ col, const float* __restrict__ inv,
                          const f16* __restrict__ C,
                          const unsigned* __restrict__ Wp116, const float* __restrict__ bp1,
                          const float* __restrict__ Wp2, const float* __restrict__ bp2,
                          float* __restrict__ out) {
    __shared__ uint4 hsh[128];
    int t = threadIdx.x;
    int lane = t & 63;
    int wv = t >> 6;
    int wid = (blockIdx.x * blockDim.x + t) >> 6;
    int m0 = wid << 2;
    int m = m0 + (lane >> 4);
    int ff = lane & 7;
    int el = (lane >> 3) & 1;

    int e = rs[m], en = re[m];
    int en4 = e + ((en - e + 3) & ~3);
    int bnd = ((m >> 8) + 1) * SLAB;
    if (en4 > bnd) en4 = bnd;

    float a0 = 0.f, a1 = 0.f, a2 = 0.f, a3 = 0.f;
    float a4 = 0.f, a5 = 0.f, a6 = 0.f, a7 = 0.f;
    qgp((const uint2*)An8, col, e, en, en4, ff, el, a0, a1, a2, a3, a4, a5, a6, a7);

    a0 += __shfl_xor(a0, 8); a1 += __shfl_xor(a1, 8);
    a2 += __shfl_xor(a2, 8); a3 += __shfl_xor(a3, 8);
    a4 += __shfl_xor(a4, 8); a5 += __shfl_xor(a5, 8);
    a6 += __shfl_xor(a6, 8); a7 += __shfl_xor(a7, 8);

    float iv = inv[m];
    u32x4 cur = __builtin_nontemporal_load((const u32x4*)C + (size_t)m * 8 + ff);
    f16x2 q0 = u2h(cur.x), q1 = u2h(cur.y), q2 = u2h(cur.z), q3 = u2h(cur.w);
    f16x2 p0, p1, p2, p3;
    p0.x = (f16)fmaf(a0, iv, (float)q0.x);
    p0.y = (f16)fmaf(a1, iv, (float)q0.y);
    p1.x = (f16)fmaf(a2, iv, (float)q1.x);
    p1.y = (f16)fmaf(a3, iv, (float)q1.y);
    p2.x = (f16)fmaf(a4, iv, (float)q2.x);
    p2.y = (f16)fmaf(a5, iv, (float)q2.y);
    p3.x = (f16)fmaf(a6, iv, (float)q3.x);
    p3.y = (f16)fmaf(a7, iv, (float)q3.y);

    uint4 hv4;
    hv4.x = h2u(p0); hv4.y = h2u(p1); hv4.z = h2u(p2); hv4.w = h2u(p3);
    if (!(lane & 8)) hsh[wv * 32 + (lane >> 4) * 8 + ff] = hv4;

    float tn[4] = {0.f, 0.f, 0.f, 0.f};
#pragma unroll
    for (int j = 0; j < 8; ++j) {
        f16x2 wp0 = u2h(Wp116[(4 * j) * HID + lane]);
        f16x2 wp1 = u2h(Wp116[(4 * j + 1) * HID + lane]);
        f16x2 wp2 = u2h(Wp116[(4 * j + 2) * HID + lane]);
        f16x2 wp3 = u2h(Wp116[(4 * j + 3) * HID + lane]);
#pragma unroll
        for (int n = 0; n < 4; ++n) {
            uint4 d = hsh[wv * 32 + n * 8 + j];
            tn[n] = dot2(u2h(d.x), wp0, tn[n]);
            tn[n] = dot2(u2h(d.y), wp1, tn[n]);
            tn[n] = dot2(u2h(d.z), wp2, tn[n]);
            tn[n] = dot2(u2h(d.w), wp3, tn[n]);
        }
    }
    float b = bp1[lane], w2v = Wp2[lane];
    float r0 = fmaxf(tn[0] + b, 0.f) * w2v;
    float r1 = fmaxf(tn[1] + b, 0.f) * w2v;
    float r2 = fmaxf(tn[2] + b, 0.f) * w2v;
    float r3 = fmaxf(tn[3] + b, 0.f) * w2v;
#pragma unroll
    for (int off = 32; off > 0; off >>= 1) {
        r0 += __shfl_xor(r0, off);
        r1 += __shfl_xor(r1, off);
        r2 += __shfl_xor(r2, off);
        r3 += __shfl_xor(r3, off);
    }
    if (lane == 0) {
        float bb = bp2[0];
        __builtin_nontemporal_store(1.f / (1.f + expf(-(r0 + bb))), out + m0);
        __builtin_nontemporal_store(1.f / (1.f + expf(-(r1 + bb))), out + m0 + 1);
        __builtin_nontemporal_store(1.f / (1.f + expf(-(r2 + bb))), out + m0 + 2);
        __builtin_nontemporal_store(1.f / (1.f + expf(-(r3 + bb))), out + m0 + 3);
    }
}

extern "C" void kernel_launch(void* const* d_in, const int* in_sizes, int n_in,
                              void* d_out, int out_size, void* d_ws, size_t ws_size,
                              hipStream_t stream) {
    const float* x   = (const float*)d_in[0];
    const int* eidx  = (const int*)d_in[1];
    const float* Wn0 = (const float*)d_in[2];
    const float* bn0 = (const float*)d_in[3];
    const float* Wr0 = (const float*)d_in[4];
    const float* Wn1 = (const float*)d_in[5];
    const float* bn1 = (const float*)d_in[6];
    const float* Wr1 = (const float*)d_in[7];
    const float* Wn2 = (const float*)d_in[8];
    const float* bn2 = (const float*)d_in[9];
    const float* Wr2 = (const float*)d_in[10];
    const float* Wp1 = (const float*)d_in[11];
    const float* bp1 = (const float*)d_in[12];
    const float* Wp2 = (const float*)d_in[13];
    const float* bp2 = (const float*)d_in[14];
    float* out = (float*)d_out;

    const int* src = eidx;
    const int* dst = eidx + EE;

    char* w = (char*)d_ws;
    size_t off = 0;
    auto carve = [&](size_t bytes) -> void* {
        void* p = w + off;
        off = (off + bytes + 255) & ~(size_t)255;
        return p;
    };
    int*   rsA    = (int*)carve((size_t)NN * 4);
    int*   reA    = (int*)carve((size_t)NN * 4);
    float* inv    = (float*)carve((size_t)NN * 4);
    int*   col    = (int*)carve((size_t)BKT * SLAB * 4);   // slab layout
    int*   bfill  = (int*)carve((size_t)BKT * 4);
    unsigned* w16 = (unsigned*)carve((size_t)5 * 2048 * 4); // packed f16 weights
    unsigned char* A0 = (unsigned char*)carve((size_t)(NN + 1) * HID); // fp8 + sentinel row
    unsigned char* A1 = (unsigned char*)carve((size_t)(NN + 1) * HID);
    f16*   C      = (f16*)carve((size_t)NN * HID * 2);     // hrb f16 (own-row in place)
    unsigned* pairs = (unsigned*)carve((size_t)BKT * SLAB * 4);
    (void)ws_size;

    unsigned* Wn1_16 = w16;
    unsigned* Wr1_16 = w16 + 2048;
    unsigned* Wn2_16 = w16 + 4096;
    unsigned* Wr2_16 = w16 + 6144;
    unsigned* Wp1_16 = w16 + 8192;

    hipMemsetAsync(bfill, 0, (size_t)BKT * 4, stream);

    // merged: CSR placement || layer-0 transform (+ weight pack + sentinels)
    mt_kernel<<<NWG + TB, 256, 0, stream>>>(src, dst, bfill, pairs,
                                            x, Wn0, bn0, Wr0, A0, C, A1,
                                            Wn1, Wr1, Wn2, Wr2, Wp1, w16);
    // per-bucket counting sort (+ x4 sentinel padding)
    build_kernel<<<BKT, 256, 0, stream>>>(pairs, bfill, rsA, reA, inv, col);

    // gather0 + transform1 (reads A0, writes A1 + C)
    gt_kernel<<<TB, 256, 0, stream>>>(A0, rsA, reA, col, inv, C, Wn1_16, bn1, Wr1_16, A1);
    // gather1 + transform2 (reads A1, writes A0 + C)
    gt_kernel<<<TB, 256, 0, stream>>>(A1, rsA, reA, col, inv, C, Wn2_16, bn2, Wr2_16, A0);
    // gather2 + head (reads A0 + C, writes out)
    gh_kernel<<<TB, 256, 0, stream>>>(A0, rsA, reA, col, inv, C, Wp1_16, bp1, Wp2, bp2, out);
}

// Round 9
// 243.849 us; speedup vs baseline: 1.4251x; 1.4251x over previous
//
#include <hip/hip_runtime.h>
#include <math.h>

#define NN 100000
#define EE 1600000
#define HID 64
#define BKT 391                 // ceil(NN/256) buckets of 256 nodes
#define SLAB 5504               // slab capacity per bucket (mean true ~4092, padded ~4476)
#define SLAB_IT ((SLAB + 255) / 256)     // 22 per-thread iterations in build
#define CHUNK 4096              // edges per workgroup in placement pass
#define NWG ((EE + CHUNK - 1) / CHUNK)   // 391
#define TB (NN / 16)            // 6250 gather/transform blocks (4 waves x 4 nodes)

typedef _Float16 f16;
typedef _Float16 f16x2 __attribute__((ext_vector_type(2)));

__device__ __forceinline__ f16x2 u2h(unsigned u) { return __builtin_bit_cast(f16x2, u); }
__device__ __forceinline__ unsigned h2u(f16x2 h) { return __builtin_bit_cast(unsigned, h); }

#if defined(__has_builtin) && __has_builtin(__builtin_amdgcn_fdot2)
__device__ __forceinline__ float dot2(f16x2 a, f16x2 b, float c) {
    return __builtin_amdgcn_fdot2(a, b, c, false);
}
#else
__device__ __forceinline__ float dot2(f16x2 a, f16x2 b, float c) {
    c = fmaf((float)a.x, (float)b.x, c);
    return fmaf((float)a.y, (float)b.y, c);
}
#endif

// ===================== fp8 (OCP e4m3) helpers (r18, kept) =====================
// Ladder: r18 fp8 -3%; r19 VMEM 16->10/batch -11%; r20 paired rows ~-2us on
// gathers; r21 nt REGRESSED +100us (nt byte stores bypass L2 write-coalescing:
// WRITE_SIZE 40->70MB on mt; no FETCH benefit). r22 = r20-best minus all nt.

#if defined(__has_builtin)
#if __has_builtin(__builtin_amdgcn_cvt_pk_f32_fp8) && __has_builtin(__builtin_amdgcn_cvt_pk_fp8_f32)
#define HW_FP8 1
#endif
#endif

#ifndef HW_FP8
__device__ __forceinline__ float dec_e4m3(unsigned b) {
    unsigned s = b >> 7, e = (b >> 3) & 0xF, m = b & 7;
    float v;
    if (e == 0) v = (float)m * 0.001953125f;                 // m * 2^-9
    else v = (1.f + (float)m * 0.125f) * exp2f((float)((int)e - 7));
    return s ? -v : v;
}
__device__ __forceinline__ unsigned char enc_e4m3(float x) {
    unsigned s = (__builtin_bit_cast(unsigned, x) >> 31) << 7;
    float a = fabsf(x);
    if (!(a < 464.f)) return (unsigned char)(s | 0x7E);      // clamp / NaN->max
    int e; float m = frexpf(a, &e);                          // a = m*2^e, m in [0.5,1)
    int E = e - 1;
    unsigned bits;
    if (E < -6) {
        int n = (int)rintf(a * 512.f);
        bits = (n > 7) ? 0x08u : (unsigned)n;
    } else {
        int n = (int)rintf((2.f * m - 1.f) * 8.f);
        if (n == 8) { n = 0; E += 1; }
        if (E > 8) return (unsigned char)(s | 0x7E);
        bits = ((unsigned)(E + 7) << 3) | (unsigned)n;
    }
    return (unsigned char)(s | bits);
}
#endif

__device__ __forceinline__ void acc_fp8(unsigned v, float& a0, float& a1,
                                        float& a2, float& a3) {
#ifdef HW_FP8
    auto lo = __builtin_amdgcn_cvt_pk_f32_fp8((int)v, false);
    auto hi = __builtin_amdgcn_cvt_pk_f32_fp8((int)v, true);
    a0 += lo[0]; a1 += lo[1]; a2 += hi[0]; a3 += hi[1];
#else
    a0 += dec_e4m3(v & 0xFFu);         a1 += dec_e4m3((v >> 8) & 0xFFu);
    a2 += dec_e4m3((v >> 16) & 0xFFu); a3 += dec_e4m3(v >> 24);
#endif
}

__device__ __forceinline__ unsigned char enc_fp8(float x) {
#ifdef HW_FP8
    return (unsigned char)(__builtin_amdgcn_cvt_pk_fp8_f32(x, x, 0, false) & 0xFF);
#else
    return enc_e4m3(x);
#endif
}

// ================= merged: CSR placement (blocks 0..NWG-1) ====================
// ================= || layer-0 transform + weight pack (blocks NWG..) ==========
// 4 nodes/wave transform (proven 49.8us; r20's 8n regressed to 53). Sentinel
// zero-rows folded in (block bb==40) -> two memset dispatches removed. Plain
// stores everywhere (r21: nt byte stores write through, +75% WRITE_SIZE).

__global__ void mt_kernel(const int* __restrict__ src, const int* __restrict__ dst,
                          int* __restrict__ bfill, unsigned* __restrict__ pairs,
                          const float* __restrict__ h,
                          const float* __restrict__ Wn, const float* __restrict__ bn,
                          const float* __restrict__ Wr,
                          unsigned char* __restrict__ hn8, f16* __restrict__ hrb,
                          unsigned char* __restrict__ hn8b,
                          const float* __restrict__ Wn1, const float* __restrict__ Wr1,
                          const float* __restrict__ Wn2, const float* __restrict__ Wr2,
                          const float* __restrict__ Wp1, unsigned* __restrict__ w16) {
    __shared__ int lc[BKT];
    __shared__ int lbase[BKT];
    int t = threadIdx.x;

    if (blockIdx.x < NWG) {
        // ---- CSR placement (bucketized; r16 proved random scatter >100us) ----
        for (int b = t; b < BKT; b += 256) lc[b] = 0;
        __syncthreads();
        int base = blockIdx.x * CHUNK;
        int myd[CHUNK / 256];
        int myr[CHUNK / 256];
#pragma unroll
        for (int j = 0; j < CHUNK / 256; ++j) {
            int i = base + j * 256 + t;
            myd[j] = (i < EE) ? dst[i] : -1;
            myr[j] = (myd[j] >= 0) ? atomicAdd(&lc[myd[j] >> 8], 1) : 0;
        }
        __syncthreads();
        for (int b = t; b < BKT; b += 256) {
            int c = lc[b];
            if (c) {
                int ofs = atomicAdd(&bfill[b], c);
                if (ofs + c > SLAB) ofs = SLAB - c;   // statistically unreachable
                lbase[b] = b * SLAB + ofs;
            }
        }
        __syncthreads();
#pragma unroll
        for (int j = 0; j < CHUNK / 256; ++j) {
            int i = base + j * 256 + t;
            if (myd[j] >= 0) {
                int b = myd[j] >> 8;
                pairs[lbase[b] + myr[j]] = (unsigned)src[i] | ((unsigned)(myd[j] & 255) << 24);
            }
        }
        return;
    }

    int bb = blockIdx.x - NWG;

    // ---- f16 weight pack (first 40 transform blocks) ----
    if (bb < 40) {
        int id = bb * 256 + t;
        int mat = id >> 11;            // 0..4
        int p = (id >> 6) & 31;        // pair index
        int j = id & 63;               // output column
        const float* W = (mat == 0) ? Wn1 : (mat == 1) ? Wr1 :
                         (mat == 2) ? Wn2 : (mat == 3) ? Wr2 : Wp1;
        f16x2 v;
        v.x = (f16)W[(2 * p) * HID + j];
        v.y = (f16)W[(2 * p + 1) * HID + j];
        w16[id] = h2u(v);
    }
    // ---- sentinel zero rows (x4-padding target, node NN) ----
    if (bb == 40 && t < 32) {
        if (t < 16) ((unsigned*)(hn8  + (size_t)NN * HID))[t] = 0;
        else        ((unsigned*)(hn8b + (size_t)NN * HID))[t - 16] = 0;
    }

    // ---- layer-0 transform: 4 nodes/wave, lane = output column ----
    int lane = t & 63;
    int wid = (bb * 256 + t) >> 6;
    int m0 = __builtin_amdgcn_readfirstlane(wid << 2);
    const float* h0 = h + (size_t)m0 * 32;

    float an0 = 0.f, an1 = 0.f, an2 = 0.f, an3 = 0.f;
    float ar0 = 0.f, ar1 = 0.f, ar2 = 0.f, ar3 = 0.f;
#pragma unroll
    for (int k = 0; k < 32; ++k) {
        float wn = Wn[k * HID + lane];
        float wr = Wr[k * HID + lane];
        float hk0 = h0[k], hk1 = h0[32 + k], hk2 = h0[64 + k], hk3 = h0[96 + k];
        an0 = fmaf(hk0, wn, an0); ar0 = fmaf(hk0, wr, ar0);
        an1 = fmaf(hk1, wn, an1); ar1 = fmaf(hk1, wr, ar1);
        an2 = fmaf(hk2, wn, an2); ar2 = fmaf(hk2, wr, ar2);
        an3 = fmaf(hk3, wn, an3); ar3 = fmaf(hk3, wr, ar3);
    }
    float b = bn[lane];
    size_t o8 = (size_t)m0 * HID + lane;        // fp8: 1 byte per feature
    size_t o = (size_t)m0 * HID + lane;
    hn8[o8] = enc_fp8(an0);
    hn8[o8 + HID] = enc_fp8(an1);
    hn8[o8 + 2 * HID] = enc_fp8(an2);
    hn8[o8 + 3 * HID] = enc_fp8(an3);
    hrb[o] = (f16)(ar0 + b); hrb[o + HID] = (f16)(ar1 + b);
    hrb[o + 2 * HID] = (f16)(ar2 + b); hrb[o + 3 * HID] = (f16)(ar3 + b);
}

// ================= per-bucket counting sort (r17 register form) ===============
// r19: per-node segments padded to x4 with sentinel node NN (zero row). rs/re
// keep the TRUE range; slots [re, rs+pad4) hold NN. inv uses true count.

__global__ void build_kernel(const unsigned* __restrict__ pairs,
                             const int* __restrict__ bfill,
                             int* __restrict__ rs, int* __restrict__ re,
                             float* __restrict__ inv, int* __restrict__ col) {
    __shared__ int ncnt[256];
    __shared__ int nexcl[256];
    int b = blockIdx.x;
    int t = threadIdx.x;
    int s0 = b * SLAB;
    int ce = bfill[b]; if (ce > SLAB) ce = SLAB;
    ncnt[t] = 0;
    __syncthreads();
    unsigned mypk[SLAB_IT];
    int myr[SLAB_IT];
#pragma unroll
    for (int j = 0; j < SLAB_IT; ++j) {
        int e = j * 256 + t;
        if (e < ce) {
            unsigned pk = pairs[s0 + e];
            mypk[j] = pk;
            myr[j] = atomicAdd(&ncnt[pk >> 24], 1);
        }
    }
    __syncthreads();
    int c = ncnt[t];                  // true count
    int c4 = (c + 3) & ~3;            // padded count
    nexcl[t] = c4;
    __syncthreads();
    for (int off = 1; off < 256; off <<= 1) {
        int u = (t >= off) ? nexcl[t - off] : 0;
        __syncthreads();
        nexcl[t] += u;
        __syncthreads();
    }
    int excl = nexcl[t] - c4;         // padded exclusive base
    int node = (b << 8) + t;
    if (node < NN) {
        int start = s0 + excl; if (start > s0 + SLAB) start = s0 + SLAB;
        int end = start + c;   if (end > s0 + SLAB) end = s0 + SLAB;
        rs[node] = start;
        re[node] = end;
        inv[node] = (c > 0) ? (1.0f / (float)c) : 0.0f;
    }
    __syncthreads();
    ncnt[t] = excl;          // repurpose: per-key padded exclusive base
    __syncthreads();
#pragma unroll
    for (int j = 0; j < SLAB_IT; ++j) {
        int e = j * 256 + t;
        if (e < ce) {
            unsigned pk = mypk[j];
            int idx = s0 + ncnt[pk >> 24] + myr[j];
            if (idx < s0 + SLAB) col[idx] = (int)(pk & 0xFFFFFFu);
        }
    }
    // sentinel pads (zero row NN): slots [excl+c, excl+c4)
    for (int k = c; k < c4; ++k) {
        int idx = s0 + excl + k;
        if (idx < s0 + SLAB) col[idx] = NN;
    }
}

// ================= paired quarter-wave gather, fp8 rows =======================
// r20 structure: quarter = 2 edge-slots x 8 lanes, uint2 row loads (2 edges/
// instr), int4 col loads -> 6 VMEM per 8-edge batch. Slots combined by one
// shfl_xor(8) per accumulator. Plain (cached) loads throughout.

__device__ __forceinline__ void acc8(uint2 v, float& a0, float& a1, float& a2,
                                     float& a3, float& a4, float& a5, float& a6,
                                     float& a7) {
    acc_fp8(v.x, a0, a1, a2, a3);
    acc_fp8(v.y, a4, a5, a6, a7);
}

__device__ __forceinline__ void qgp(const uint2* __restrict__ rp2,
                                    const int* __restrict__ col,
                                    int e, int en, int en4, int ff, int el,
                                    float& a0, float& a1, float& a2, float& a3,
                                    float& a4, float& a5, float& a6, float& a7) {
    while (e + 8 <= en4) {
        int4 ca = *(const int4*)(col + e);
        int4 cb = *(const int4*)(col + e + 4);
        int c0 = el ? ca.y : ca.x;
        int c1 = el ? ca.w : ca.z;
        int c2 = el ? cb.y : cb.x;
        int c3 = el ? cb.w : cb.z;
        uint2 v0 = rp2[(size_t)c0 * 8 + ff];
        uint2 v1 = rp2[(size_t)c1 * 8 + ff];
        uint2 v2 = rp2[(size_t)c2 * 8 + ff];
        uint2 v3 = rp2[(size_t)c3 * 8 + ff];
        acc8(v0, a0, a1, a2, a3, a4, a5, a6, a7);
        acc8(v1, a0, a1, a2, a3, a4, a5, a6, a7);
        acc8(v2, a0, a1, a2, a3, a4, a5, a6, a7);
        acc8(v3, a0, a1, a2, a3, a4, a5, a6, a7);
        e += 8;
    }
    if (e + 4 <= en4) {
        int4 ca = *(const int4*)(col + e);
        int c0 = el ? ca.y : ca.x;
        int c1 = el ? ca.w : ca.z;
        uint2 v0 = rp2[(size_t)c0 * 8 + ff];
        uint2 v1 = rp2[(size_t)c1 * 8 + ff];
        acc8(v0, a0, a1, a2, a3, a4, a5, a6, a7);
        acc8(v1, a0, a1, a2, a3, a4, a5, a6, a7);
        e += 4;
    }
    while (e < en) {                  // only reachable if pad clamp fired
        if (!el) {
            uint2 v = rp2[(size_t)col[e] * 8 + ff];
            acc8(v, a0, a1, a2, a3, a4, a5, a6, a7);
        }
        ++e;
    }
}

// ================= fused gather_k + transform_{k+1} ===========================
// hsh byte layout = r19 (node row = 128B linear f16); uniform-address b128
// reads broadcast. Only slot-0 lanes write hsh.

__global__ void gt_kernel(const unsigned char* __restrict__ An8,
                          const int* __restrict__ rs, const int* __restrict__ re,
                          const int* __restrict__ col, const float* __restrict__ inv,
                          f16* C,
                          const unsigned* __restrict__ Wn16, const float* __restrict__ bn,
                          const unsigned* __restrict__ Wr16,
                          unsigned char* __restrict__ Aout8) {
    __shared__ uint4 hsh[128];        // 4 waves x 4 nodes x 8 uint4 = 2KB
    int t = threadIdx.x;
    int lane = t & 63;
    int wv = t >> 6;
    int wid = (blockIdx.x * blockDim.x + t) >> 6;
    int m0 = wid << 2;
    int m = m0 + (lane >> 4);
    int ff = lane & 7;
    int el = (lane >> 3) & 1;

    int e = rs[m], en = re[m];
    int en4 = e + ((en - e + 3) & ~3);
    int bnd = ((m >> 8) + 1) * SLAB;
    if (en4 > bnd) en4 = bnd;

    float a0 = 0.f, a1 = 0.f, a2 = 0.f, a3 = 0.f;
    float a4 = 0.f, a5 = 0.f, a6 = 0.f, a7 = 0.f;
    qgp((const uint2*)An8, col, e, en, en4, ff, el, a0, a1, a2, a3, a4, a5, a6, a7);

    // combine edge slots (lanes fl and fl^8)
    a0 += __shfl_xor(a0, 8); a1 += __shfl_xor(a1, 8);
    a2 += __shfl_xor(a2, 8); a3 += __shfl_xor(a3, 8);
    a4 += __shfl_xor(a4, 8); a5 += __shfl_xor(a5, 8);
    a6 += __shfl_xor(a6, 8); a7 += __shfl_xor(a7, 8);

    // h_{k+1}[m] = relu(inv*agg + hrb_k[m]); lane (ff) holds feats 8ff..8ff+7
    float iv = inv[m];
    uint4 cur = ((const uint4*)C)[(size_t)m * 8 + ff];
    f16x2 q0 = u2h(cur.x), q1 = u2h(cur.y), q2 = u2h(cur.z), q3 = u2h(cur.w);
    f16x2 p0, p1, p2, p3;
    p0.x = (f16)fmaxf(fmaf(a0, iv, (float)q0.x), 0.f);
    p0.y = (f16)fmaxf(fmaf(a1, iv, (float)q0.y), 0.f);
    p1.x = (f16)fmaxf(fmaf(a2, iv, (float)q1.x), 0.f);
    p1.y = (f16)fmaxf(fmaf(a3, iv, (float)q1.y), 0.f);
    p2.x = (f16)fmaxf(fmaf(a4, iv, (float)q2.x), 0.f);
    p2.y = (f16)fmaxf(fmaf(a5, iv, (float)q2.y), 0.f);
    p3.x = (f16)fmaxf(fmaf(a6, iv, (float)q3.x), 0.f);
    p3.y = (f16)fmaxf(fmaf(a7, iv, (float)q3.y), 0.f);

    uint4 hv4;
    hv4.x = h2u(p0); hv4.y = h2u(p1); hv4.z = h2u(p2); hv4.w = h2u(p3);
    if (!(lane & 8)) hsh[wv * 32 + (lane >> 4) * 8 + ff] = hv4;

    float an[4] = {0.f, 0.f, 0.f, 0.f};
    float ar[4] = {0.f, 0.f, 0.f, 0.f};
#pragma unroll
    for (int j = 0; j < 8; ++j) {     // covers kk = 2j, 2j+1
        f16x2 wn0 = u2h(Wn16[(4 * j) * HID + lane]);
        f16x2 wn1 = u2h(Wn16[(4 * j + 1) * HID + lane]);
        f16x2 wn2 = u2h(Wn16[(4 * j + 2) * HID + lane]);
        f16x2 wn3 = u2h(Wn16[(4 * j + 3) * HID + lane]);
        f16x2 wr0 = u2h(Wr16[(4 * j) * HID + lane]);
        f16x2 wr1 = u2h(Wr16[(4 * j + 1) * HID + lane]);
        f16x2 wr2 = u2h(Wr16[(4 * j + 2) * HID + lane]);
        f16x2 wr3 = u2h(Wr16[(4 * j + 3) * HID + lane]);
#pragma unroll
        for (int n = 0; n < 4; ++n) {
            uint4 d = hsh[wv * 32 + n * 8 + j];   // uniform addr -> broadcast
            an[n] = dot2(u2h(d.x), wn0, an[n]);
            an[n] = dot2(u2h(d.y), wn1, an[n]);
            an[n] = dot2(u2h(d.z), wn2, an[n]);
            an[n] = dot2(u2h(d.w), wn3, an[n]);
            ar[n] = dot2(u2h(d.x), wr0, ar[n]);
            ar[n] = dot2(u2h(d.y), wr1, ar[n]);
            ar[n] = dot2(u2h(d.z), wr2, ar[n]);
            ar[n] = dot2(u2h(d.w), wr3, ar[n]);
        }
    }
    float b = bn[lane];
    size_t o8 = (size_t)m0 * HID + lane;
    size_t o = (size_t)m0 * HID + lane;
#pragma unroll
    for (int n = 0; n < 4; ++n) {
        Aout8[o8 + n * HID] = enc_fp8(an[n]);
        C[o + n * HID] = (f16)(ar[n] + b);
    }
}

// ================= fused gather_2 (no relu) + predictor head ==================

__global__ void gh_kernel(const unsigned char* __restrict__ An8,
                          const int* __restrict__ rs, const int* __restrict__ re,
                          const int* __restrict__ col, const float* __restrict__ inv,
                          const f16* __restrict__ C,
                          const unsigned* __restrict__ Wp116, const float* __restrict__ bp1,
                          const float* __restrict__ Wp2, const float* __restrict__ bp2,
                          float* __restrict__ out) {
    __shared__ uint4 hsh[128];
    int t = threadIdx.x;
    int lane = t & 63;
    int wv = t >> 6;
    int wid = (blockIdx.x * blockDim.x + t) >> 6;
    int m0 = wid << 2;
    int m = m0 + (lane >> 4);
    int ff = lane & 7;
    int el = (lane >> 3) & 1;

    int e = rs[m], en = re[m];
    int en4 = e + ((en - e + 3) & ~3);
    int bnd = ((m >> 8) + 1) * SLAB;
    if (en4 > bnd) en4 = bnd;

    float a0 = 0.f, a1 = 0.f, a2 = 0.f, a3 = 0.f;
    float a4 = 0.f, a5 = 0.f, a6 = 0.f, a7 = 0.f;
    qgp((const uint2*)An8, col, e, en, en4, ff, el, a0, a1, a2, a3, a4, a5, a6, a7);

    a0 += __shfl_xor(a0, 8); a1 += __shfl_xor(a1, 8);
    a2 += __shfl_xor(a2, 8); a3 += __shfl_xor(a3, 8);
    a4 += __shfl_xor(a4, 8); a5 += __shfl_xor(a5, 8);
    a6 += __shfl_xor(a6, 8); a7 += __shfl_xor(a7, 8);

    float iv = inv[m];
    uint4 cur = ((const uint4*)C)[(size_t)m * 8 + ff];
    f16x2 q0 = u2h(cur.x), q1 = u2h(cur.y), q2 = u2h(cur.z), q3 = u2h(cur.w);
    f16x2 p0, p1, p2, p3;
    p0.x = (f16)fmaf(a0, iv, (float)q0.x);
    p0.y = (f16)fmaf(a1, iv, (float)q0.y);
    p1.x = (f16)fmaf(a2, iv, (float)q1.x);
    p1.y = (f16)fmaf(a3, iv, (float)q1.y);
    p2.x = (f16)fmaf(a4, iv, (float)q2.x);
    p2.y = (f16)fmaf(a5, iv, (float)q2.y);
    p3.x = (f16)fmaf(a6, iv, (float)q3.x);
    p3.y = (f16)fmaf(a7, iv, (float)q3.y);

    uint4 hv4;
    hv4.x = h2u(p0); hv4.y = h2u(p1); hv4.z = h2u(p2); hv4.w = h2u(p3);
    if (!(lane & 8)) hsh[wv * 32 + (lane >> 4) * 8 + ff] = hv4;

    float tn[4] = {0.f, 0.f, 0.f, 0.f};
#pragma unroll
    for (int j = 0; j < 8; ++j) {
        f16x2 wp0 = u2h(Wp116[(4 * j) * HID + lane]);
        f16x2 wp1 = u2h(Wp116[(4 * j + 1) * HID + lane]);
        f16x2 wp2 = u2h(Wp116[(4 * j + 2) * HID + lane]);
        f16x2 wp3 = u2h(Wp116[(4 * j + 3) * HID + lane]);
#pragma unroll
        for (int n = 0; n < 4; ++n) {
            uint4 d = hsh[wv * 32 + n * 8 + j];
            tn[n] = dot2(u2h(d.x), wp0, tn[n]);
            tn[n] = dot2(u2h(d.y), wp1, tn[n]);
            tn[n] = dot2(u2h(d.z), wp2, tn[n]);
            tn[n] = dot2(u2h(d.w), wp3, tn[n]);
        }
    }
    float b = bp1[lane], w2v = Wp2[lane];
    float r0 = fmaxf(tn[0] + b, 0.f) * w2v;
    float r1 = fmaxf(tn[1] + b, 0.f) * w2v;
    float r2 = fmaxf(tn[2] + b, 0.f) * w2v;
    float r3 = fmaxf(tn[3] + b, 0.f) * w2v;
#pragma unroll
    for (int off = 32; off > 0; off >>= 1) {
        r0 += __shfl_xor(r0, off);
        r1 += __shfl_xor(r1, off);
        r2 += __shfl_xor(r2, off);
        r3 += __shfl_xor(r3, off);
    }
    if (lane == 0) {
        float bb = bp2[0];
        out[m0]     = 1.f / (1.f + expf(-(r0 + bb)));
        out[m0 + 1] = 1.f / (1.f + expf(-(r1 + bb)));
        out[m0 + 2] = 1.f / (1.f + expf(-(r2 + bb)));
        out[m0 + 3] = 1.f / (1.f + expf(-(r3 + bb)));
    }
}

extern "C" void kernel_launch(void* const* d_in, const int* in_sizes, int n_in,
                              void* d_out, int out_size, void* d_ws, size_t ws_size,
                              hipStream_t stream) {
    const float* x   = (const float*)d_in[0];
    const int* eidx  = (const int*)d_in[1];
    const float* Wn0 = (const float*)d_in[2];
    const float* bn0 = (const float*)d_in[3];
    const float* Wr0 = (const float*)d_in[4];
    const float* Wn1 = (const float*)d_in[5];
    const float* bn1 = (const float*)d_in[6];
    const float* Wr1 = (const float*)d_in[7];
    const float* Wn2 = (const float*)d_in[8];
    const float* bn2 = (const float*)d_in[9];
    const float* Wr2 = (const float*)d_in[10];
    const float* Wp1 = (const float*)d_in[11];
    const float* bp1 = (const float*)d_in[12];
    const float* Wp2 = (const float*)d_in[13];
    const float* bp2 = (const float*)d_in[14];
    float* out = (float*)d_out;

    const int* src = eidx;
    const int* dst = eidx + EE;

    char* w = (char*)d_ws;
    size_t off = 0;
    auto carve = [&](size_t bytes) -> void* {
        void* p = w + off;
        off = (off + bytes + 255) & ~(size_t)255;
        return p;
    };
    int*   rsA    = (int*)carve((size_t)NN * 4);
    int*   reA    = (int*)carve((size_t)NN * 4);
    float* inv    = (float*)carve((size_t)NN * 4);
    int*   col    = (int*)carve((size_t)BKT * SLAB * 4);   // slab layout
    int*   bfill  = (int*)carve((size_t)BKT * 4);
    unsigned* w16 = (unsigned*)carve((size_t)5 * 2048 * 4); // packed f16 weights
    unsigned char* A0 = (unsigned char*)carve((size_t)(NN + 1) * HID); // fp8 + sentinel row
    unsigned char* A1 = (unsigned char*)carve((size_t)(NN + 1) * HID);
    f16*   C      = (f16*)carve((size_t)NN * HID * 2);     // hrb f16 (own-row in place)
    unsigned* pairs = (unsigned*)carve((size_t)BKT * SLAB * 4);
    (void)ws_size;

    unsigned* Wn1_16 = w16;
    unsigned* Wr1_16 = w16 + 2048;
    unsigned* Wn2_16 = w16 + 4096;
    unsigned* Wr2_16 = w16 + 6144;
    unsigned* Wp1_16 = w16 + 8192;

    hipMemsetAsync(bfill, 0, (size_t)BKT * 4, stream);

    // merged: CSR placement || layer-0 transform (+ weight pack + sentinels)
    mt_kernel<<<NWG + TB, 256, 0, stream>>>(src, dst, bfill, pairs,
                                            x, Wn0, bn0, Wr0, A0, C, A1,
                                            Wn1, Wr1, Wn2, Wr2, Wp1, w16);
    // per-bucket counting sort (+ x4 sentinel padding)
    build_kernel<<<BKT, 256, 0, stream>>>(pairs, bfill, rsA, reA, inv, col);

    // gather0 + transform1 (reads A0, writes A1 + C)
    gt_kernel<<<TB, 256, 0, stream>>>(A0, rsA, reA, col, inv, C, Wn1_16, bn1, Wr1_16, A1);
    // gather1 + transform2 (reads A1, writes A0 + C)
    gt_kernel<<<TB, 256, 0, stream>>>(A1, rsA, reA, col, inv, C, Wn2_16, bn2, Wr2_16, A0);
    // gather2 + head (reads A0 + C, writes out)
    gh_kernel<<<TB, 256, 0, stream>>>(A0, rsA, reA, col, inv, C, Wp1_16, bp1, Wp2, bp2, out);
}